// Round 1
// baseline (900.542 us; speedup 1.0000x reference)
//
#include <hip/hip_runtime.h>
#include <hip/hip_bf16.h>

// Bilinear sparse interpolation.
// x:   [B=16, C=64, Hx=240, Wx=320] fp32
// pos: [B, N=20000, 2] fp32 (x,y) in original image coords (W=1280, H=960)
// out: [B, N, C] fp32
//
// Mapping: one block = 256 threads = 4 points x 64 channels.
// lane c (t & 63) handles channel c -> out[b][n][c] store is coalesced
// (64 consecutive fp32 = 256B per point). Gather loads are strided by the
// channel-plane size (307KB) across lanes -- inherently scattered; rely on
// L1/L2/L3 for corner-pair locality.

#define BQ 4  // points per block

__global__ __launch_bounds__(256) void interp_sparse2d_kernel(
    const float* __restrict__ x,
    const float* __restrict__ pos,
    const int* __restrict__ Hp,
    const int* __restrict__ Wp,
    float* __restrict__ out,
    int N) {
  constexpr int C = 64;
  constexpr int Hx = 240;
  constexpr int Wx = 320;

  const int t = threadIdx.x;
  const int c = t & 63;
  const int p = blockIdx.x * BQ + (t >> 6);
  const int b = blockIdx.y;
  if (p >= N) return;

  const float Wf = (float)Wp[0];
  const float Hf = (float)Hp[0];

  // pos[b][p][0], pos[b][p][1]
  const float* pp = pos + ((size_t)b * N + p) * 2;
  const float px_raw = pp[0];
  const float py_raw = pp[1];

  // match reference: pos * (Wx-1) / W   (keep real division, no fast-math)
  const float px = px_raw * (float)(Wx - 1) / Wf;
  const float py = py_raw * (float)(Hx - 1) / Hf;

  int x0 = (int)floorf(px);
  int y0 = (int)floorf(py);
  x0 = min(max(x0, 0), Wx - 1);
  y0 = min(max(y0, 0), Hx - 1);
  const int x1 = min(x0 + 1, Wx - 1);
  const int y1 = min(y0 + 1, Hx - 1);

  const float x0f = (float)x0, x1f = (float)x1;
  const float y0f = (float)y0, y1f = (float)y1;

  const float wa = (x1f - px) * (y1f - py);
  const float wb = (x1f - px) * (py - y0f);
  const float wc = (px - x0f) * (y1f - py);
  const float wd = (px - x0f) * (py - y0f);

  // channel plane base: x[((b*C + c)*Hx)*Wx]
  const float* plane = x + ((size_t)(b * C + c) * Hx) * Wx;
  const int r0 = y0 * Wx;
  const int r1 = y1 * Wx;

  const float Ia = plane[r0 + x0];
  const float Ib = plane[r1 + x0];
  const float Ic = plane[r0 + x1];
  const float Id = plane[r1 + x1];

  const float v = wa * Ia + wb * Ib + wc * Ic + wd * Id;

  out[((size_t)b * N + p) * C + c] = v;
}

extern "C" void kernel_launch(void* const* d_in, const int* in_sizes, int n_in,
                              void* d_out, int out_size, void* d_ws, size_t ws_size,
                              hipStream_t stream) {
  const float* x = (const float*)d_in[0];
  const float* pos = (const float*)d_in[1];
  const int* Hp = (const int*)d_in[2];
  const int* Wp = (const int*)d_in[3];
  float* out = (float*)d_out;

  const int B = 16;
  const int N = in_sizes[1] / (B * 2);  // pos has B*N*2 elements

  dim3 grid((N + BQ - 1) / BQ, B);
  dim3 block(256);
  interp_sparse2d_kernel<<<grid, block, 0, stream>>>(x, pos, Hp, Wp, out, N);
}

// Round 2
// 555.752 us; speedup vs baseline: 1.6204x; 1.6204x over previous
//
#include <hip/hip_runtime.h>
#include <hip/hip_bf16.h>

// Bilinear sparse interpolation, two-pass:
//  1) transpose x [B,C,Hx,Wx] -> xT [B,Hx,Wx,C] in d_ws (LDS-tiled, coalesced)
//  2) gather: wave = 64 channels of one point -> each corner is one
//     contiguous 256B read from xT. 4 corners = 1KB/point, no line waste.
//
// Round-1 evidence: FETCH_SIZE 2.12GB vs 318MB ideal (7x over-fetch) because
// NCHW gathers touch 64 lines/corner-row. NHWC fixes the fetch amplification.

constexpr int C_ = 64;
constexpr int Hx_ = 240;
constexpr int Wx_ = 320;
constexpr int HW_ = Hx_ * Wx_;

// ---- pass 1: NCHW -> NHWC transpose ---------------------------------------
// block = 256 threads, tile = 64 hw-positions x 64 channels (16.6 KB LDS).
// load : lanes vary hw (contiguous 256B per wave, per channel row)
// store: lanes vary c  (contiguous 256B per wave, per hw position)
// LDS pad 65: both phases <=2-way bank aliasing (free on gfx950).
__global__ __launch_bounds__(256) void transpose_nchw_nhwc(
    const float* __restrict__ x, float* __restrict__ xT) {
  __shared__ float tile[64][65];
  const int t = threadIdx.x;
  const int lane = t & 63;
  const int grp = t >> 6;  // 0..3
  const int hw0 = blockIdx.x * 64;
  const int b = blockIdx.y;

  const float* xin = x + (size_t)b * C_ * HW_;
  float* xout = xT + (size_t)b * HW_ * C_;

#pragma unroll
  for (int i = 0; i < 16; ++i) {
    const int c = grp * 16 + i;
    tile[lane][c] = xin[(size_t)c * HW_ + hw0 + lane];
  }
  __syncthreads();
#pragma unroll
  for (int j = 0; j < 16; ++j) {
    const int hw = grp * 16 + j;
    xout[(size_t)(hw0 + hw) * C_ + lane] = tile[hw][lane];
  }
}

// ---- pass 2: gather from NHWC ---------------------------------------------
#define BQ 4  // points per block

__global__ __launch_bounds__(256) void gather_nhwc(
    const float* __restrict__ xT, const float* __restrict__ pos,
    const int* __restrict__ Hp, const int* __restrict__ Wp,
    float* __restrict__ out, int N) {
  const int t = threadIdx.x;
  const int c = t & 63;
  const int p = blockIdx.x * BQ + (t >> 6);
  const int b = blockIdx.y;
  if (p >= N) return;

  const float Wf = (float)Wp[0];
  const float Hf = (float)Hp[0];

  const float* pp = pos + ((size_t)b * N + p) * 2;
  const float px = pp[0] * (float)(Wx_ - 1) / Wf;
  const float py = pp[1] * (float)(Hx_ - 1) / Hf;

  int x0 = min(max((int)floorf(px), 0), Wx_ - 1);
  int y0 = min(max((int)floorf(py), 0), Hx_ - 1);
  const int x1 = min(x0 + 1, Wx_ - 1);
  const int y1 = min(y0 + 1, Hx_ - 1);

  const float x0f = (float)x0, x1f = (float)x1;
  const float y0f = (float)y0, y1f = (float)y1;
  const float wa = (x1f - px) * (y1f - py);
  const float wb = (x1f - px) * (py - y0f);
  const float wc = (px - x0f) * (y1f - py);
  const float wd = (px - x0f) * (py - y0f);

  const float* base = xT + (size_t)b * HW_ * C_;
  const float Ia = base[(size_t)(y0 * Wx_ + x0) * C_ + c];
  const float Ib = base[(size_t)(y1 * Wx_ + x0) * C_ + c];
  const float Ic = base[(size_t)(y0 * Wx_ + x1) * C_ + c];
  const float Id = base[(size_t)(y1 * Wx_ + x1) * C_ + c];

  out[((size_t)b * N + p) * C_ + c] = wa * Ia + wb * Ib + wc * Ic + wd * Id;
}

// ---- fallback (round-1 direct NCHW gather) if ws too small ----------------
__global__ __launch_bounds__(256) void gather_nchw_direct(
    const float* __restrict__ x, const float* __restrict__ pos,
    const int* __restrict__ Hp, const int* __restrict__ Wp,
    float* __restrict__ out, int N) {
  const int t = threadIdx.x;
  const int c = t & 63;
  const int p = blockIdx.x * BQ + (t >> 6);
  const int b = blockIdx.y;
  if (p >= N) return;

  const float Wf = (float)Wp[0];
  const float Hf = (float)Hp[0];
  const float* pp = pos + ((size_t)b * N + p) * 2;
  const float px = pp[0] * (float)(Wx_ - 1) / Wf;
  const float py = pp[1] * (float)(Hx_ - 1) / Hf;

  int x0 = min(max((int)floorf(px), 0), Wx_ - 1);
  int y0 = min(max((int)floorf(py), 0), Hx_ - 1);
  const int x1 = min(x0 + 1, Wx_ - 1);
  const int y1 = min(y0 + 1, Hx_ - 1);

  const float x0f = (float)x0, x1f = (float)x1;
  const float y0f = (float)y0, y1f = (float)y1;
  const float wa = (x1f - px) * (y1f - py);
  const float wb = (x1f - px) * (py - y0f);
  const float wc = (px - x0f) * (y1f - py);
  const float wd = (px - x0f) * (py - y0f);

  const float* plane = x + (size_t)(b * C_ + c) * HW_;
  const int r0 = y0 * Wx_;
  const int r1 = y1 * Wx_;
  const float Ia = plane[r0 + x0];
  const float Ib = plane[r1 + x0];
  const float Ic = plane[r0 + x1];
  const float Id = plane[r1 + x1];

  out[((size_t)b * N + p) * C_ + c] = wa * Ia + wb * Ib + wc * Ic + wd * Id;
}

extern "C" void kernel_launch(void* const* d_in, const int* in_sizes, int n_in,
                              void* d_out, int out_size, void* d_ws, size_t ws_size,
                              hipStream_t stream) {
  const float* x = (const float*)d_in[0];
  const float* pos = (const float*)d_in[1];
  const int* Hp = (const int*)d_in[2];
  const int* Wp = (const int*)d_in[3];
  float* out = (float*)d_out;

  const int B = 16;
  const int N = in_sizes[1] / (B * 2);

  const size_t need = (size_t)B * C_ * HW_ * sizeof(float);  // 314.6 MB
  if (ws_size >= need) {
    float* xT = (float*)d_ws;
    dim3 tgrid(HW_ / 64, B);  // 76800/64 = 1200 tiles per batch
    transpose_nchw_nhwc<<<tgrid, 256, 0, stream>>>(x, xT);
    dim3 ggrid((N + BQ - 1) / BQ, B);
    gather_nhwc<<<ggrid, 256, 0, stream>>>(xT, pos, Hp, Wp, out, N);
  } else {
    dim3 ggrid((N + BQ - 1) / BQ, B);
    gather_nchw_direct<<<ggrid, 256, 0, stream>>>(x, pos, Hp, Wp, out, N);
  }
}

// Round 3
// 523.685 us; speedup vs baseline: 1.7196x; 1.0612x over previous
//
#include <hip/hip_runtime.h>
#include <hip/hip_bf16.h>

// Bilinear sparse interpolation, two-pass with bf16 intermediate:
//  1) transpose x [B,C,Hx,Wx] fp32 -> xT [B,Hx,Wx,C] bf16 in d_ws
//     (157 MB -- fits in the 256 MB Infinity Cache)
//  2) gather: wave = 64 channels of one point; each corner is one
//     contiguous 128B bf16 read from xT. fp32 weights/accum, fp32 out.
//
// R1 evidence: NCHW gather = 7x HBM over-fetch (2.12 GB).
// R2 evidence: fp32 transpose+gather = ~245us, on the HBM roofline of its
// own 1.36 GB data flow -> shrink bytes via bf16 xT (+L3 residency).

constexpr int C_ = 64;
constexpr int Hx_ = 240;
constexpr int Wx_ = 320;
constexpr int HW_ = Hx_ * Wx_;

static __device__ __forceinline__ unsigned short f2bf_raw(float v) {
  __hip_bfloat16 h = __float2bfloat16(v);
  return *reinterpret_cast<unsigned short*>(&h);
}

// ---- pass 1: NCHW fp32 -> NHWC bf16 transpose -----------------------------
// block = 256 threads, tile = 64 hw x 64 c. LDS row stride 66 ushorts (132B,
// 4B-aligned, 33 dwords -> consecutive hw rows shift 1 bank).
// load : lanes vary hw -> 256B contiguous global reads per wave
// store: ushort2 per thread, wave covers 64 consecutive pairs -> 256B stores
__global__ __launch_bounds__(256) void transpose_nchw_nhwc_bf16(
    const float* __restrict__ x, unsigned short* __restrict__ xT) {
  __shared__ unsigned short tile[64 * 66];
  const int t = threadIdx.x;
  const int hw_l = t & 63;
  const int cg = t >> 6;  // 0..3
  const int hw0 = blockIdx.x * 64;
  const int b = blockIdx.y;

  const float* xin = x + (size_t)b * C_ * HW_ + hw0;
#pragma unroll
  for (int i = 0; i < 16; ++i) {
    const int c = i * 4 + cg;
    const float v = xin[(size_t)c * HW_ + hw_l];
    tile[hw_l * 66 + c] = f2bf_raw(v);
  }
  __syncthreads();

  // xout viewed as uint (=2 bf16). element index = hw*32 + cpair
  unsigned int* xout =
      (unsigned int*)(xT + (size_t)b * HW_ * C_ + (size_t)hw0 * C_);
#pragma unroll
  for (int j = 0; j < 8; ++j) {
    const int idx = j * 256 + t;  // pair index 0..2047
    const int hw = idx >> 5;
    const int cp = idx & 31;
    const unsigned int pair =
        *reinterpret_cast<const unsigned int*>(&tile[hw * 66 + cp * 2]);
    xout[hw * 32 + cp] = pair;
  }
}

// ---- pass 2: gather from NHWC bf16 ----------------------------------------
#define BQ 4  // points per block

__global__ __launch_bounds__(256) void gather_nhwc_bf16(
    const unsigned short* __restrict__ xT, const float* __restrict__ pos,
    const int* __restrict__ Hp, const int* __restrict__ Wp,
    float* __restrict__ out, int N) {
  const int t = threadIdx.x;
  const int c = t & 63;
  const int p = blockIdx.x * BQ + (t >> 6);
  const int b = blockIdx.y;
  if (p >= N) return;

  const float Wf = (float)Wp[0];
  const float Hf = (float)Hp[0];

  const float* pp = pos + ((size_t)b * N + p) * 2;
  const float px = pp[0] * (float)(Wx_ - 1) / Wf;
  const float py = pp[1] * (float)(Hx_ - 1) / Hf;

  int x0 = min(max((int)floorf(px), 0), Wx_ - 1);
  int y0 = min(max((int)floorf(py), 0), Hx_ - 1);
  const int x1 = min(x0 + 1, Wx_ - 1);
  const int y1 = min(y0 + 1, Hx_ - 1);

  const float x0f = (float)x0, x1f = (float)x1;
  const float y0f = (float)y0, y1f = (float)y1;
  const float wa = (x1f - px) * (y1f - py);
  const float wb = (x1f - px) * (py - y0f);
  const float wc = (px - x0f) * (y1f - py);
  const float wd = (px - x0f) * (py - y0f);

  const unsigned short* base = xT + (size_t)b * HW_ * C_;
  const unsigned short ua = base[(size_t)(y0 * Wx_ + x0) * C_ + c];
  const unsigned short ub = base[(size_t)(y1 * Wx_ + x0) * C_ + c];
  const unsigned short uc = base[(size_t)(y0 * Wx_ + x1) * C_ + c];
  const unsigned short ud = base[(size_t)(y1 * Wx_ + x1) * C_ + c];

  // bf16 raw -> float: shift into high half
  const float Ia = __uint_as_float((unsigned int)ua << 16);
  const float Ib = __uint_as_float((unsigned int)ub << 16);
  const float Ic = __uint_as_float((unsigned int)uc << 16);
  const float Id = __uint_as_float((unsigned int)ud << 16);

  out[((size_t)b * N + p) * C_ + c] = wa * Ia + wb * Ib + wc * Ic + wd * Id;
}

// ---- fallback (direct NCHW gather) if ws too small ------------------------
__global__ __launch_bounds__(256) void gather_nchw_direct(
    const float* __restrict__ x, const float* __restrict__ pos,
    const int* __restrict__ Hp, const int* __restrict__ Wp,
    float* __restrict__ out, int N) {
  const int t = threadIdx.x;
  const int c = t & 63;
  const int p = blockIdx.x * BQ + (t >> 6);
  const int b = blockIdx.y;
  if (p >= N) return;

  const float Wf = (float)Wp[0];
  const float Hf = (float)Hp[0];
  const float* pp = pos + ((size_t)b * N + p) * 2;
  const float px = pp[0] * (float)(Wx_ - 1) / Wf;
  const float py = pp[1] * (float)(Hx_ - 1) / Hf;

  int x0 = min(max((int)floorf(px), 0), Wx_ - 1);
  int y0 = min(max((int)floorf(py), 0), Hx_ - 1);
  const int x1 = min(x0 + 1, Wx_ - 1);
  const int y1 = min(y0 + 1, Hx_ - 1);

  const float x0f = (float)x0, x1f = (float)x1;
  const float y0f = (float)y0, y1f = (float)y1;
  const float wa = (x1f - px) * (y1f - py);
  const float wb = (x1f - px) * (py - y0f);
  const float wc = (px - x0f) * (y1f - py);
  const float wd = (px - x0f) * (py - y0f);

  const float* plane = x + (size_t)(b * C_ + c) * HW_;
  const int r0 = y0 * Wx_;
  const int r1 = y1 * Wx_;
  const float Ia = plane[r0 + x0];
  const float Ib = plane[r1 + x0];
  const float Ic = plane[r0 + x1];
  const float Id = plane[r1 + x1];

  out[((size_t)b * N + p) * C_ + c] = wa * Ia + wb * Ib + wc * Ic + wd * Id;
}

extern "C" void kernel_launch(void* const* d_in, const int* in_sizes, int n_in,
                              void* d_out, int out_size, void* d_ws, size_t ws_size,
                              hipStream_t stream) {
  const float* x = (const float*)d_in[0];
  const float* pos = (const float*)d_in[1];
  const int* Hp = (const int*)d_in[2];
  const int* Wp = (const int*)d_in[3];
  float* out = (float*)d_out;

  const int B = 16;
  const int N = in_sizes[1] / (B * 2);

  const size_t need = (size_t)B * C_ * HW_ * sizeof(unsigned short);  // 157 MB
  if (ws_size >= need) {
    unsigned short* xT = (unsigned short*)d_ws;
    dim3 tgrid(HW_ / 64, B);  // 1200 x 16
    transpose_nchw_nhwc_bf16<<<tgrid, 256, 0, stream>>>(x, xT);
    dim3 ggrid((N + BQ - 1) / BQ, B);
    gather_nhwc_bf16<<<ggrid, 256, 0, stream>>>(xT, pos, Hp, Wp, out, N);
  } else {
    dim3 ggrid((N + BQ - 1) / BQ, B);
    gather_nchw_direct<<<ggrid, 256, 0, stream>>>(x, pos, Hp, Wp, out, N);
  }
}